// Round 2
// baseline (498.523 us; speedup 1.0000x reference)
//
#include <hip/hip_runtime.h>

// VQ-VAE VectorQuantizer: x[32,32,32,256] fp32, embeddings[256,1024] fp32.
// out = quantized (straight-through passes values through), loss = 1.25*mean((q-x)^2).
//
// Round 2: emulate the numpy fp32 reference's rounding EXACTLY.
// distances = fl32( fl32(A - 2B) + C ),  A=||x||^2 (numpy pairwise sum),
// C=||e||^2 (sequential axis-0 sum), B=x.e (sequential fp32 fma).
// Scores ~256 -> fp32 ulp 3e-5; near-ties MUST round like numpy or argmin flips.

#define D 256
#define K 1024
#define N_PTS 32768
#define KT 32        // codes per LDS tile
#define KSPLIT 4     // K-range splits (512 blocks)
#define KPER (K / KSPLIT)

// ws layout (bytes):
//   [0, 4096)            float enorm32[K]        (numpy-sequential fp32 ||e||^2)
//   [8192, 8200)         double loss accumulator
//   [16384, +512KiB)     float bestscore[N_PTS][KSPLIT]
//   [16384+512KiB, ...)  int   bestidx [N_PTS][KSPLIT]

__global__ __launch_bounds__(256) void vq_enorm(const float* __restrict__ emb,
                                                float* __restrict__ enorm32) {
    int k = blockIdx.x * 256 + threadIdx.x;
    // numpy: np.sum(emb*emb, axis=0) -> outer-axis reduce = SEQUENTIAL over d,
    // each square rounded fp32 first. No FMA contraction allowed.
    float c = 0.0f;
    for (int d = 0; d < D; ++d) {
        float e = emb[d * K + k];
        c = __fadd_rn(c, __fmul_rn(e, e));
    }
    enorm32[k] = c;
}

__global__ __launch_bounds__(256) void vq_scores(const float* __restrict__ x,
                                                 const float* __restrict__ emb,
                                                 const float* __restrict__ enorm32,
                                                 float* __restrict__ bestscore,
                                                 int* __restrict__ bestidx) {
    __shared__ float etile[D * KT];   // 32 KiB
    const int ks  = blockIdx.x & (KSPLIT - 1);
    const int pg  = blockIdx.x >> 2;
    const int tid = threadIdx.x;
    const int n   = pg * 256 + tid;
    const float4* __restrict__ x4 = reinterpret_cast<const float4*>(x + (size_t)n * D);

    // ---- A = numpy pairwise fp32 sum of fl(x*x) over 256 elements ----
    // numpy: n=256 > 128 -> split 128+128; each 128-block: 8 accumulators,
    // r[j] init from first 8, 15 strided adds, combine ((r0+r1)+(r2+r3))+((r4+r5)+(r6+r7)).
    float A;
    {
        float ah[2];
        #pragma unroll
        for (int h = 0; h < 2; ++h) {
            float r[8];
            float4 u = x4[h * 32 + 0], v = x4[h * 32 + 1];
            r[0] = __fmul_rn(u.x, u.x); r[1] = __fmul_rn(u.y, u.y);
            r[2] = __fmul_rn(u.z, u.z); r[3] = __fmul_rn(u.w, u.w);
            r[4] = __fmul_rn(v.x, v.x); r[5] = __fmul_rn(v.y, v.y);
            r[6] = __fmul_rn(v.z, v.z); r[7] = __fmul_rn(v.w, v.w);
            #pragma unroll
            for (int i = 1; i < 16; ++i) {
                u = x4[h * 32 + 2 * i]; v = x4[h * 32 + 2 * i + 1];
                r[0] = __fadd_rn(r[0], __fmul_rn(u.x, u.x));
                r[1] = __fadd_rn(r[1], __fmul_rn(u.y, u.y));
                r[2] = __fadd_rn(r[2], __fmul_rn(u.z, u.z));
                r[3] = __fadd_rn(r[3], __fmul_rn(u.w, u.w));
                r[4] = __fadd_rn(r[4], __fmul_rn(v.x, v.x));
                r[5] = __fadd_rn(r[5], __fmul_rn(v.y, v.y));
                r[6] = __fadd_rn(r[6], __fmul_rn(v.z, v.z));
                r[7] = __fadd_rn(r[7], __fmul_rn(v.w, v.w));
            }
            ah[h] = __fadd_rn(__fadd_rn(__fadd_rn(r[0], r[1]), __fadd_rn(r[2], r[3])),
                              __fadd_rn(__fadd_rn(r[4], r[5]), __fadd_rn(r[6], r[7])));
        }
        A = __fadd_rn(ah[0], ah[1]);
    }

    float best = 1e30f;
    int bidx = 0;
    const int kbase = ks * KPER;

    for (int t = 0; t < KPER / KT; ++t) {
        const int k0 = kbase + t * KT;
        __syncthreads();
        #pragma unroll
        for (int s = 0; s < (D * KT) / 256; ++s) {
            int li = s * 256 + tid;
            int d = li >> 5, j = li & 31;
            etile[d * KT + j] = emb[d * K + k0 + j];
        }
        __syncthreads();

        float acc[KT];
        #pragma unroll
        for (int j = 0; j < KT; ++j) acc[j] = 0.0f;

        // B: sequential fp32 FMA over ascending d (closest guess at BLAS sgemm).
        // etile reads are wave-uniform -> LDS broadcast, conflict-free.
        const float4* et4 = reinterpret_cast<const float4*>(etile);
        for (int d4 = 0; d4 < D / 4; ++d4) {
            float4 xv = x4[d4];
#define DO_U(XS, DD)                                                     \
            {                                                            \
                float xs = (XS);                                         \
                _Pragma("unroll")                                        \
                for (int jj = 0; jj < KT / 4; ++jj) {                    \
                    float4 e4 = et4[(DD) * (KT / 4) + jj];               \
                    acc[4 * jj + 0] = fmaf(xs, e4.x, acc[4 * jj + 0]);   \
                    acc[4 * jj + 1] = fmaf(xs, e4.y, acc[4 * jj + 1]);   \
                    acc[4 * jj + 2] = fmaf(xs, e4.z, acc[4 * jj + 2]);   \
                    acc[4 * jj + 3] = fmaf(xs, e4.w, acc[4 * jj + 3]);   \
                }                                                        \
            }
            DO_U(xv.x, d4 * 4 + 0)
            DO_U(xv.y, d4 * 4 + 1)
            DO_U(xv.z, d4 * 4 + 2)
            DO_U(xv.w, d4 * 4 + 3)
#undef DO_U
        }

        #pragma unroll
        for (int j = 0; j < KT; ++j) {
            // numpy: dist = fl32( fl32(A - 2B) + C )  -- two roundings at ~256 scale
            float twoB = 2.0f * acc[j];                       // exact *2
            float dist = __fadd_rn(__fsub_rn(A, twoB), enorm32[k0 + j]);
            if (dist < best) { best = dist; bidx = k0 + j; }  // strict <: first idx wins
        }
    }
    bestscore[n * KSPLIT + ks] = best;
    bestidx[n * KSPLIT + ks]   = bidx;
}

__global__ __launch_bounds__(256) void vq_merge(const float* __restrict__ x,
                                                const float* __restrict__ emb,
                                                const float* __restrict__ bestscore,
                                                const int* __restrict__ bestidx,
                                                float* __restrict__ out,
                                                double* __restrict__ lossacc) {
    const int n = blockIdx.x * 256 + threadIdx.x;
    float best = 1e30f;
    int bi = 0;
    #pragma unroll
    for (int s = 0; s < KSPLIT; ++s) {   // ascending splits + strict <  => global first-min
        float sc = bestscore[(size_t)n * KSPLIT + s];
        int id = bestidx[(size_t)n * KSPLIT + s];
        if (sc < best) { best = sc; bi = id; }
    }

    const float4* x4 = reinterpret_cast<const float4*>(x + (size_t)n * D);
    float4* o4 = reinterpret_cast<float4*>(out + (size_t)n * D);
    double lsum = 0.0;
    for (int d4 = 0; d4 < D / 4; ++d4) {
        float4 xv = x4[d4];
        float4 q;   // emb column gather, L2-resident (emb = 1 MiB)
        q.x = emb[(d4 * 4 + 0) * K + bi];
        q.y = emb[(d4 * 4 + 1) * K + bi];
        q.z = emb[(d4 * 4 + 2) * K + bi];
        q.w = emb[(d4 * 4 + 3) * K + bi];
        o4[d4] = q;   // exact pass-through of selected code
        double dx;
        dx = (double)q.x - (double)xv.x; lsum = fma(dx, dx, lsum);
        dx = (double)q.y - (double)xv.y; lsum = fma(dx, dx, lsum);
        dx = (double)q.z - (double)xv.z; lsum = fma(dx, dx, lsum);
        dx = (double)q.w - (double)xv.w; lsum = fma(dx, dx, lsum);
    }
    for (int off = 32; off > 0; off >>= 1) lsum += __shfl_down(lsum, off);
    if ((threadIdx.x & 63) == 0) atomicAdd(lossacc, lsum);
}

__global__ void vq_loss(const double* __restrict__ lossacc, float* __restrict__ out_loss) {
    if (threadIdx.x == 0 && blockIdx.x == 0) {
        out_loss[0] = (float)(1.25 * (lossacc[0] / (double)((size_t)N_PTS * D)));
    }
}

extern "C" void kernel_launch(void* const* d_in, const int* in_sizes, int n_in,
                              void* d_out, int out_size, void* d_ws, size_t ws_size,
                              hipStream_t stream) {
    const float* x   = (const float*)d_in[0];
    const float* emb = (const float*)d_in[1];
    float* out = (float*)d_out;
    char* ws = (char*)d_ws;

    float*  enorm32   = (float*)(ws);
    double* lossacc   = (double*)(ws + 8192);
    float*  bestscore = (float*)(ws + 16384);
    int*    bestidx   = (int*)(ws + 16384 + (size_t)N_PTS * KSPLIT * sizeof(float));

    hipMemsetAsync(lossacc, 0, sizeof(double), stream);
    vq_enorm<<<K / 256, 256, 0, stream>>>(emb, enorm32);
    vq_scores<<<(N_PTS / 256) * KSPLIT, 256, 0, stream>>>(x, emb, enorm32, bestscore, bestidx);
    vq_merge<<<N_PTS / 256, 256, 0, stream>>>(x, emb, bestscore, bestidx, out, lossacc);
    vq_loss<<<1, 64, 0, stream>>>(lossacc, out + (size_t)N_PTS * D);
}

// Round 3
// 382.868 us; speedup vs baseline: 1.3021x; 1.3021x over previous
//
#include <hip/hip_runtime.h>

// VQ-VAE VectorQuantizer: x[32768,256] fp32, emb[256,1024] fp32.
// Round 3: GEMM-register-tiled scores (bit-identical arithmetic to round 2's
// passing kernel: same sequential-d fmaf chain per (n,k), same fl32 rounding
// dist = fl(fl(A-2B)+C), same first-index argmin semantics).

#define D 256
#define K 1024
#define N_PTS 32768
#define KSPLIT 4
#define KPER (K / KSPLIT)          // 256 codes per split
#define NT 64                      // rows per block
#define DT 16                      // d per LDS tile
#define CG_STRIDE (DT * 16 + 4)    // 260 floats: 16B-aligned, banks spread 2-way

// ws layout (bytes):
//   0        float  enorm32[1024]          (4 KB)
//   8192     double lossacc                (8 B)
//   16384    float  Anorm[32768]           (128 KB)
//   147456   float  embT[1024][256]        (1 MB)
//   1196032  float  bestscore[32768][4]    (512 KB)
//   1720320  int    bestidx [32768][4]     (512 KB)

__global__ __launch_bounds__(256) void vq_enorm(const float* __restrict__ emb,
                                                float* __restrict__ enorm32) {
    int k = blockIdx.x * 256 + threadIdx.x;
    // numpy np.sum(emb*emb, axis=0): sequential over d, square rounded first.
    float c = 0.0f;
    for (int d = 0; d < D; ++d) {
        float e = emb[d * K + k];
        c = __fadd_rn(c, __fmul_rn(e, e));
    }
    enorm32[k] = c;
}

__global__ __launch_bounds__(256) void vq_anorm(const float* __restrict__ x,
                                                float* __restrict__ Anorm) {
    const int n = blockIdx.x * 256 + threadIdx.x;
    const float4* __restrict__ x4 = reinterpret_cast<const float4*>(x + (size_t)n * D);
    // numpy pairwise fp32 sum of fl(x*x), n=256: two 128-blocks, 8 accumulators
    // each, combine ((r0+r1)+(r2+r3))+((r4+r5)+(r6+r7)), then halves.
    float ah[2];
    #pragma unroll
    for (int h = 0; h < 2; ++h) {
        float r[8];
        float4 u = x4[h * 32 + 0], v = x4[h * 32 + 1];
        r[0] = __fmul_rn(u.x, u.x); r[1] = __fmul_rn(u.y, u.y);
        r[2] = __fmul_rn(u.z, u.z); r[3] = __fmul_rn(u.w, u.w);
        r[4] = __fmul_rn(v.x, v.x); r[5] = __fmul_rn(v.y, v.y);
        r[6] = __fmul_rn(v.z, v.z); r[7] = __fmul_rn(v.w, v.w);
        #pragma unroll
        for (int i = 1; i < 16; ++i) {
            u = x4[h * 32 + 2 * i]; v = x4[h * 32 + 2 * i + 1];
            r[0] = __fadd_rn(r[0], __fmul_rn(u.x, u.x));
            r[1] = __fadd_rn(r[1], __fmul_rn(u.y, u.y));
            r[2] = __fadd_rn(r[2], __fmul_rn(u.z, u.z));
            r[3] = __fadd_rn(r[3], __fmul_rn(u.w, u.w));
            r[4] = __fadd_rn(r[4], __fmul_rn(v.x, v.x));
            r[5] = __fadd_rn(r[5], __fmul_rn(v.y, v.y));
            r[6] = __fadd_rn(r[6], __fmul_rn(v.z, v.z));
            r[7] = __fadd_rn(r[7], __fmul_rn(v.w, v.w));
        }
        ah[h] = __fadd_rn(__fadd_rn(__fadd_rn(r[0], r[1]), __fadd_rn(r[2], r[3])),
                          __fadd_rn(__fadd_rn(r[4], r[5]), __fadd_rn(r[6], r[7])));
    }
    Anorm[n] = __fadd_rn(ah[0], ah[1]);
}

// one-time emb transpose: embT[k][d] = emb[d][k]  (for coalesced merge gather)
__global__ __launch_bounds__(256) void vq_embT(const float* __restrict__ emb,
                                               float* __restrict__ embT) {
    __shared__ float tile[64][68];     // +4 pad breaks read-side conflicts
    const int bk = blockIdx.x >> 2, bd = blockIdx.x & 3;
    const int k0 = bk * 64, d0 = bd * 64;
    const int t = threadIdx.x;
    #pragma unroll
    for (int s = 0; s < 4; ++s) {
        int li = s * 256 + t;
        int dd = li >> 4, kq = li & 15;
        float4 v = *reinterpret_cast<const float4*>(&emb[(size_t)(d0 + dd) * K + k0 + kq * 4]);
        tile[dd][kq * 4 + 0] = v.x; tile[dd][kq * 4 + 1] = v.y;
        tile[dd][kq * 4 + 2] = v.z; tile[dd][kq * 4 + 3] = v.w;
    }
    __syncthreads();
    #pragma unroll
    for (int s = 0; s < 4; ++s) {
        int li = s * 256 + t;
        int kk = li >> 4, dq = li & 15;
        float4 v;
        v.x = tile[dq * 4 + 0][kk]; v.y = tile[dq * 4 + 1][kk];
        v.z = tile[dq * 4 + 2][kk]; v.w = tile[dq * 4 + 3][kk];
        *reinterpret_cast<float4*>(&embT[(size_t)(k0 + kk) * D + d0 + dq * 4]) = v;
    }
}

__global__ __launch_bounds__(256, 4) void vq_scores(const float* __restrict__ x,
                                                    const float* __restrict__ emb,
                                                    const float* __restrict__ enorm32,
                                                    const float* __restrict__ Anorm,
                                                    float* __restrict__ bestscore,
                                                    int* __restrict__ bestidx) {
    __shared__ float e_lds[16 * CG_STRIDE];  // 16.6 KB: [cg][dd][16 codes]+pad
    __shared__ float x_t[DT * NT];           // 4 KB:   [dd][64 rows]
    const int tid = threadIdx.x;
    const int rt = blockIdx.x >> 2;          // 512 row tiles
    const int ks = blockIdx.x & 3;           // 4 code splits
    const int n0 = rt * NT;
    const int k0 = ks * KPER;
    const int rg = tid >> 4;                 // 16 row groups of 4 rows
    const int cg = tid & 15;                 // 16 code groups of 16 codes

    float acc[4][16];
    #pragma unroll
    for (int r = 0; r < 4; ++r)
        #pragma unroll
        for (int j = 0; j < 16; ++j) acc[r][j] = 0.0f;

    for (int t = 0; t < D / DT; ++t) {
        const int d0 = t * DT;
        __syncthreads();
        // stage e tile: [cg][dd][16] with 16B pad per cg block (2-way banks)
        #pragma unroll
        for (int s = 0; s < 4; ++s) {
            int li = s * 256 + tid;
            int dd = li >> 6, m4 = li & 63;
            float4 ev = *reinterpret_cast<const float4*>(
                &emb[(size_t)(d0 + dd) * K + k0 + m4 * 4]);
            *reinterpret_cast<float4*>(
                &e_lds[(m4 >> 2) * CG_STRIDE + dd * 16 + (m4 & 3) * 4]) = ev;
        }
        // stage x tile transposed: x_t[dd][row]
        {
            int row = tid >> 2, dq = tid & 3;
            float4 xv = *reinterpret_cast<const float4*>(
                &x[(size_t)(n0 + row) * D + d0 + dq * 4]);
            x_t[(dq * 4 + 0) * NT + row] = xv.x;
            x_t[(dq * 4 + 1) * NT + row] = xv.y;
            x_t[(dq * 4 + 2) * NT + row] = xv.z;
            x_t[(dq * 4 + 3) * NT + row] = xv.w;
        }
        __syncthreads();

        // d ascending (tiles asc + dd asc): per-(n,k) fmaf chain identical to r2
        #pragma unroll 4
        for (int dd = 0; dd < DT; ++dd) {
            float4 xv = *reinterpret_cast<const float4*>(&x_t[dd * NT + rg * 4]);
            #pragma unroll
            for (int jj = 0; jj < 4; ++jj) {
                float4 ev = *reinterpret_cast<const float4*>(
                    &e_lds[cg * CG_STRIDE + dd * 16 + jj * 4]);
                acc[0][jj*4+0] = fmaf(xv.x, ev.x, acc[0][jj*4+0]);
                acc[0][jj*4+1] = fmaf(xv.x, ev.y, acc[0][jj*4+1]);
                acc[0][jj*4+2] = fmaf(xv.x, ev.z, acc[0][jj*4+2]);
                acc[0][jj*4+3] = fmaf(xv.x, ev.w, acc[0][jj*4+3]);
                acc[1][jj*4+0] = fmaf(xv.y, ev.x, acc[1][jj*4+0]);
                acc[1][jj*4+1] = fmaf(xv.y, ev.y, acc[1][jj*4+1]);
                acc[1][jj*4+2] = fmaf(xv.y, ev.z, acc[1][jj*4+2]);
                acc[1][jj*4+3] = fmaf(xv.y, ev.w, acc[1][jj*4+3]);
                acc[2][jj*4+0] = fmaf(xv.z, ev.x, acc[2][jj*4+0]);
                acc[2][jj*4+1] = fmaf(xv.z, ev.y, acc[2][jj*4+1]);
                acc[2][jj*4+2] = fmaf(xv.z, ev.z, acc[2][jj*4+2]);
                acc[2][jj*4+3] = fmaf(xv.z, ev.w, acc[2][jj*4+3]);
                acc[3][jj*4+0] = fmaf(xv.w, ev.x, acc[3][jj*4+0]);
                acc[3][jj*4+1] = fmaf(xv.w, ev.y, acc[3][jj*4+1]);
                acc[3][jj*4+2] = fmaf(xv.w, ev.z, acc[3][jj*4+2]);
                acc[3][jj*4+3] = fmaf(xv.w, ev.w, acc[3][jj*4+3]);
            }
        }
    }

    // epilogue: numpy rounding fl(fl(A-2B)+C); first-index argmin per split
    float cc[16];
    #pragma unroll
    for (int j4 = 0; j4 < 4; ++j4)
        *reinterpret_cast<float4*>(&cc[j4 * 4]) =
            *reinterpret_cast<const float4*>(&enorm32[k0 + cg * 16 + j4 * 4]);

    #pragma unroll
    for (int r = 0; r < 4; ++r) {
        const int n = n0 + rg * 4 + r;
        const float A = Anorm[n];
        float best = 1e30f; int bidx = 0;
        #pragma unroll
        for (int j = 0; j < 16; ++j) {
            float dist = __fadd_rn(__fsub_rn(A, 2.0f * acc[r][j]), cc[j]);
            if (dist < best) { best = dist; bidx = k0 + cg * 16 + j; }
        }
        // reduce over the 16 code-group lanes of this row (xor within group)
        #pragma unroll
        for (int m = 1; m <= 8; m <<= 1) {
            float os = __shfl_xor(best, m);
            int   oi = __shfl_xor(bidx, m);
            if (os < best || (os == best && oi < bidx)) { best = os; bidx = oi; }
        }
        if (cg == 0) {
            bestscore[(size_t)n * KSPLIT + ks] = best;
            bestidx[(size_t)n * KSPLIT + ks]   = bidx;
        }
    }
}

__global__ __launch_bounds__(256) void vq_merge(const float* __restrict__ x,
                                                const float* __restrict__ embT,
                                                const float* __restrict__ bestscore,
                                                const int* __restrict__ bestidx,
                                                float* __restrict__ out,
                                                double* __restrict__ lossacc) {
    const int tid = threadIdx.x;
    const int n  = blockIdx.x * 64 + (tid >> 2);   // 4 lanes per row
    const int dq = tid & 3;
    float best = 1e30f; int bi = 0;
    #pragma unroll
    for (int s = 0; s < KSPLIT; ++s) {   // ascending splits + strict <
        float sc = bestscore[(size_t)n * KSPLIT + s];
        int   id = bestidx[(size_t)n * KSPLIT + s];
        if (sc < best) { best = sc; bi = id; }
    }
    const float4* x4 = reinterpret_cast<const float4*>(x + (size_t)n * D);
    const float4* e4 = reinterpret_cast<const float4*>(embT + (size_t)bi * D);
    float4* o4 = reinterpret_cast<float4*>(out + (size_t)n * D);
    double lsum = 0.0;
    #pragma unroll
    for (int i = 0; i < 16; ++i) {
        int idx = i * 4 + dq;          // 4 lanes cover 64B contiguous per row
        float4 xv = x4[idx];
        float4 q  = e4[idx];
        o4[idx] = q;                   // exact pass-through of selected code
        double dxx;
        dxx = (double)q.x - (double)xv.x; lsum = fma(dxx, dxx, lsum);
        dxx = (double)q.y - (double)xv.y; lsum = fma(dxx, dxx, lsum);
        dxx = (double)q.z - (double)xv.z; lsum = fma(dxx, dxx, lsum);
        dxx = (double)q.w - (double)xv.w; lsum = fma(dxx, dxx, lsum);
    }
    for (int off = 32; off > 0; off >>= 1) lsum += __shfl_down(lsum, off);
    if ((tid & 63) == 0) atomicAdd(lossacc, lsum);
}

__global__ void vq_loss(const double* __restrict__ lossacc, float* __restrict__ out_loss) {
    if (threadIdx.x == 0 && blockIdx.x == 0) {
        out_loss[0] = (float)(1.25 * (lossacc[0] / (double)((size_t)N_PTS * D)));
    }
}

extern "C" void kernel_launch(void* const* d_in, const int* in_sizes, int n_in,
                              void* d_out, int out_size, void* d_ws, size_t ws_size,
                              hipStream_t stream) {
    const float* x   = (const float*)d_in[0];
    const float* emb = (const float*)d_in[1];
    float* out = (float*)d_out;
    char* ws = (char*)d_ws;

    float*  enorm32   = (float*)(ws);
    double* lossacc   = (double*)(ws + 8192);
    float*  Anorm     = (float*)(ws + 16384);
    float*  embT      = (float*)(ws + 147456);
    float*  bestscore = (float*)(ws + 1196032);
    int*    bestidx   = (int*)(ws + 1720320);

    hipMemsetAsync(lossacc, 0, sizeof(double), stream);
    vq_enorm<<<K / 256, 256, 0, stream>>>(emb, enorm32);
    vq_anorm<<<N_PTS / 256, 256, 0, stream>>>(x, Anorm);
    vq_embT<<<64, 256, 0, stream>>>(emb, embT);
    vq_scores<<<(N_PTS / NT) * KSPLIT, 256, 0, stream>>>(x, emb, enorm32, Anorm,
                                                         bestscore, bestidx);
    vq_merge<<<N_PTS / 64, 256, 0, stream>>>(x, embT, bestscore, bestidx, out, lossacc);
    vq_loss<<<1, 64, 0, stream>>>(lossacc, out + (size_t)N_PTS * D);
}